// Round 5
// baseline (271.636 us; speedup 1.0000x reference)
//
#include <hip/hip_runtime.h>
#include <hip/hip_bf16.h>

#define B_   8
#define LQ_  2048
#define LK_  2048
#define D_   128
#define QBLK 64
#define KBLK 64
#define THREADS 512
#define SCALE 0.08838834764831845f              // 1/sqrt(128)
#define NEGL2E (-1.44269504088896340736f * SCALE) // -log2(e)/sqrt(128)

typedef __attribute__((ext_vector_type(8))) __bf16 bf16x8;  // MFMA A/B frag
typedef __attribute__((ext_vector_type(4))) float  f32x4;   // MFMA C/D frag
typedef __attribute__((ext_vector_type(4))) float  fx4;
typedef __attribute__((ext_vector_type(4))) int    i32x4;

// ---------------- prep: K f32 -> bf16 row-major ----------------
__global__ __launch_bounds__(256)
void kprep(const float* __restrict__ k, __bf16* __restrict__ kb)
{
    size_t i = ((size_t)blockIdx.x * 256 + threadIdx.x) * 8;
    fx4 a = *(const fx4*)(k + i);
    fx4 b = *(const fx4*)(k + i + 4);
    bf16x8 w;
#pragma unroll
    for (int j = 0; j < 4; ++j) { w[j] = (__bf16)a[j]; w[4 + j] = (__bf16)b[j]; }
    *(bf16x8*)(kb + i) = w;
}

// ---------------- prep: V f32 -> Vt[d][k] bf16, slot-permuted ----------------
// slot s (within 32-key group): s = g*8 + h*4 + j  <-  key = h*16 + g*4 + j
__global__ __launch_bounds__(128)
void vprep(const float* __restrict__ v, __bf16* __restrict__ vt)
{
    const int b  = blockIdx.x & 7;
    const int k0 = (blockIdx.x >> 3) * 64;
    const int d  = threadIdx.x;                 // 0..127
    const float* vb = v + ((size_t)b * LK_ + k0) * D_ + d;
    __bf16* vr = vt + ((size_t)b * D_ + d) * LK_ + k0;
#pragma unroll
    for (int grp = 0; grp < 2; ++grp) {
#pragma unroll
        for (int g = 0; g < 4; ++g) {
            bf16x8 w;
#pragma unroll
            for (int e = 0; e < 8; ++e) {
                int h = e >> 2, j = e & 3;
                int key = grp * 32 + h * 16 + g * 4 + j;
                w[e] = (__bf16)vb[(size_t)key * D_];   // coalesced across lanes (d)
            }
            *(bf16x8*)(vr + grp * 32 + g * 8) = w;
        }
    }
}

// ---------------- main: barrier-free sigmoid attention ----------------
// 8 waves: qg = wid&1 (32 q-rows), kg = (wid>>1)&1 (32-key half of tile),
// tp = wid>>2 (tile parity). Each wave: 16 tiles, all data via L2/registers.
__global__ __launch_bounds__(THREADS, 2)
void sigattn_main(const float* __restrict__ q, const int* __restrict__ mask,
                  const __bf16* __restrict__ Kb, const __bf16* __restrict__ Vt,
                  float* __restrict__ out)
{
    __shared__ float red[64 * 132];             // epilogue only (stride 132 f32)

    const int tid  = threadIdx.x;
    const int lane = tid & 63;
    const int l15  = lane & 15;
    const int g    = lane >> 4;
    const int wid  = tid >> 6;
    const int qg   = wid & 1;
    const int kg   = (wid >> 1) & 1;
    const int tp   = wid >> 2;

    const int bid   = blockIdx.x;
    const int b     = bid & 7;                  // batch -> XCD-pinned K/V in L2
    const int q0    = (bid >> 3) * QBLK;
    const int qbase = qg * 32;

    const float*  qb = q    + ((size_t)b * LQ_ + q0) * D_;
    const int*    mb = mask + ((size_t)b * LQ_ + q0) * LK_;
    const __bf16* kb = Kb   + (size_t)b * LK_ * D_;
    const __bf16* vt = Vt   + (size_t)b * D_ * LK_;
    float*        ob = out  + ((size_t)b * LQ_ + q0) * D_;

    // Q fragments (registers, whole kernel): qfrag[qq][dblk]
    bf16x8 qfrag[2][4];
#pragma unroll
    for (int qq = 0; qq < 2; ++qq) {
        const float* qrow = qb + (size_t)(qbase + qq * 16 + l15) * D_;
#pragma unroll
        for (int dblk = 0; dblk < 4; ++dblk) {
            fx4 f0 = *(const fx4*)(qrow + dblk * 32 + g * 8);
            fx4 f1 = *(const fx4*)(qrow + dblk * 32 + g * 8 + 4);
            bf16x8 w;
#pragma unroll
            for (int j = 0; j < 4; ++j) { w[j] = (__bf16)f0[j]; w[4 + j] = (__bf16)f1[j]; }
            qfrag[qq][dblk] = w;
        }
    }

    f32x4 oacc[2][8];
#pragma unroll
    for (int qq = 0; qq < 2; ++qq)
#pragma unroll
        for (int nb = 0; nb < 8; ++nb) oacc[qq][nb] = (f32x4){0.f, 0.f, 0.f, 0.f};

    // per-lane mask row pointers (int4 = the 4 C-frag rows 4g..4g+3)
    const int* mr[2];
    mr[0] = mb + (size_t)(qbase + l15) * LK_ + kg * 32 + 4 * g;
    mr[1] = mr[0] + (size_t)16 * LK_;

    int kt = tp * KBLK;                          // this wave's first tile
    i32x4 mcur[2][2];
#pragma unroll
    for (int qq = 0; qq < 2; ++qq)
#pragma unroll
        for (int ksl = 0; ksl < 2; ++ksl)
            mcur[qq][ksl] = __builtin_nontemporal_load((const i32x4*)(mr[qq] + kt + ksl * 16));

    for (int i = 0; i < 16; ++i, kt += 2 * KBLK) {
        const int ktp = (i < 15) ? kt + 2 * KBLK : kt;   // clamped prefetch addr

        // ---- prefetch next tile's mask (HBM ~900cyc away) ----
        i32x4 mnxt[2][2];
#pragma unroll
        for (int qq = 0; qq < 2; ++qq)
#pragma unroll
            for (int ksl = 0; ksl < 2; ++ksl)
                mnxt[qq][ksl] = __builtin_nontemporal_load((const i32x4*)(mr[qq] + ktp + ksl * 16));

        // ---- K fragments from L2 ----
        bf16x8 kfr[2][4];
#pragma unroll
        for (int ksl = 0; ksl < 2; ++ksl)
#pragma unroll
            for (int dblk = 0; dblk < 4; ++dblk)
                kfr[ksl][dblk] = *(const bf16x8*)(kb + (size_t)(kt + kg * 32 + ksl * 16 + l15) * D_ + dblk * 32 + g * 8);

        // ---- V fragments from L2 (issued early; consumed after sigmoid) ----
        bf16x8 vfr[8];
#pragma unroll
        for (int nb = 0; nb < 8; ++nb)
            vfr[nb] = *(const bf16x8*)(vt + (size_t)(nb * 16 + l15) * LK_ + kt + kg * 32 + g * 8);

        // ---- QK^T swapped: sacc[qq][ksl], rows=keys, cols=q ----
        f32x4 sacc[2][2];
#pragma unroll
        for (int qq = 0; qq < 2; ++qq)
#pragma unroll
            for (int ksl = 0; ksl < 2; ++ksl)
                sacc[qq][ksl] = (f32x4){0.f, 0.f, 0.f, 0.f};
#pragma unroll
        for (int ksl = 0; ksl < 2; ++ksl)
#pragma unroll
            for (int dblk = 0; dblk < 4; ++dblk) {
                bf16x8 a = kfr[ksl][dblk];
#pragma unroll
                for (int qq = 0; qq < 2; ++qq)
                    sacc[qq][ksl] = __builtin_amdgcn_mfma_f32_16x16x32_bf16(a, qfrag[qq][dblk], sacc[qq][ksl], 0, 0, 0);
            }

        // ---- mask + sigmoid -> P fragments (registers only) ----
        bf16x8 pfrag[2];
#pragma unroll
        for (int qq = 0; qq < 2; ++qq)
#pragma unroll
            for (int ksl = 0; ksl < 2; ++ksl)
#pragma unroll
                for (int r = 0; r < 4; ++r) {
                    float e = exp2f(sacc[qq][ksl][r] * NEGL2E);
                    float p = __builtin_amdgcn_rcpf(1.0f + e);
                    p = (mcur[qq][ksl][r] != 0) ? 0.0f : p;
                    pfrag[qq][ksl * 4 + r] = (__bf16)p;
                }

        // ---- PV: oacc[qq][nb] += P * V (slot-permuted Vt matches pfrag order) ----
#pragma unroll
        for (int nb = 0; nb < 8; ++nb)
#pragma unroll
            for (int qq = 0; qq < 2; ++qq)
                oacc[qq][nb] = __builtin_amdgcn_mfma_f32_16x16x32_bf16(pfrag[qq], vfr[nb], oacc[qq][nb], 0, 0, 0);

#pragma unroll
        for (int qq = 0; qq < 2; ++qq)
#pragma unroll
            for (int ksl = 0; ksl < 2; ++ksl) mcur[qq][ksl] = mnxt[qq][ksl];
    }

    // ---------------- epilogue: 4-stage reduce over (kg, tp), then store ----------------
    if (tp == 0 && kg == 0) {
#pragma unroll
        for (int qq = 0; qq < 2; ++qq)
#pragma unroll
            for (int nb = 0; nb < 8; ++nb)
#pragma unroll
                for (int r = 0; r < 4; ++r)
                    red[(qbase + qq * 16 + 4 * g + r) * 132 + nb * 16 + l15] = oacc[qq][nb][r];
    }
    __syncthreads();
    if (tp == 0 && kg == 1) {
#pragma unroll
        for (int qq = 0; qq < 2; ++qq)
#pragma unroll
            for (int nb = 0; nb < 8; ++nb)
#pragma unroll
                for (int r = 0; r < 4; ++r)
                    red[(qbase + qq * 16 + 4 * g + r) * 132 + nb * 16 + l15] += oacc[qq][nb][r];
    }
    __syncthreads();
    if (tp == 1 && kg == 0) {
#pragma unroll
        for (int qq = 0; qq < 2; ++qq)
#pragma unroll
            for (int nb = 0; nb < 8; ++nb)
#pragma unroll
                for (int r = 0; r < 4; ++r)
                    red[(qbase + qq * 16 + 4 * g + r) * 132 + nb * 16 + l15] += oacc[qq][nb][r];
    }
    __syncthreads();
    if (tp == 1 && kg == 1) {
#pragma unroll
        for (int qq = 0; qq < 2; ++qq)
#pragma unroll
            for (int nb = 0; nb < 8; ++nb)
#pragma unroll
                for (int r = 0; r < 4; ++r)
                    red[(qbase + qq * 16 + 4 * g + r) * 132 + nb * 16 + l15] += oacc[qq][nb][r];
    }
    __syncthreads();
#pragma unroll
    for (int i2 = 0; i2 < 4; ++i2) {
        int idx = tid + i2 * THREADS;
        int row = idx >> 5, c4 = idx & 31;
        fx4 val = *(const fx4*)(red + row * 132 + c4 * 4);
        __builtin_nontemporal_store(val, (fx4*)(ob + (size_t)row * D_ + c4 * 4));
    }
}

extern "C" void kernel_launch(void* const* d_in, const int* in_sizes, int n_in,
                              void* d_out, int out_size, void* d_ws, size_t ws_size,
                              hipStream_t stream) {
    const float* q    = (const float*)d_in[0];
    const float* k    = (const float*)d_in[1];
    const float* v    = (const float*)d_in[2];
    const int*   mask = (const int*)d_in[3];
    float*       out  = (float*)d_out;

    __bf16* Kb = (__bf16*)d_ws;                        // 4 MB
    __bf16* Vt = (__bf16*)d_ws + (size_t)2097152;      // next 4 MB

    kprep<<<dim3(1024), dim3(256), 0, stream>>>(k, Kb);          // 2M elems / 8
    vprep<<<dim3(256), dim3(128), 0, stream>>>(v, Vt);           // 8 batch x 32 ktiles
    sigattn_main<<<dim3(256), dim3(THREADS), 0, stream>>>(q, mask, Kb, Vt, out);
}

// Round 6
// 233.891 us; speedup vs baseline: 1.1614x; 1.1614x over previous
//
#include <hip/hip_runtime.h>
#include <hip/hip_bf16.h>

#define B_   8
#define LQ_  2048
#define LK_  2048
#define D_   128
#define QBLK 64
#define THREADS 512
#define NITER 16                              // 128 keys per iteration
#define NEGL2E (-0.12755004910797864f)        // -log2(e)/sqrt(128)

typedef __attribute__((ext_vector_type(8))) __bf16 bf16x8;  // MFMA A/B frag
typedef __attribute__((ext_vector_type(4))) float  f32x4;   // MFMA C/D frag
typedef __attribute__((ext_vector_type(4))) float  fx4;
typedef __attribute__((ext_vector_type(4))) int    i32x4;

// ---------- prep: K -> fragment-packed bf16 ----------
// frag f = ((b*128 + kk)*4 + dblk); elem: lane(l15,g) = K[kk*16+l15][dblk*32+g*8 ..+7]
__global__ __launch_bounds__(256)
void kprep(const float* __restrict__ k, __bf16* __restrict__ kp)
{
    int id   = blockIdx.x * 256 + threadIdx.x;       // 0..262143
    int lane = id & 63;
    int f    = id >> 6;                              // 0..4095
    int dblk = f & 3, kk = (f >> 2) & 127, b = f >> 9;
    const float* src = k + ((size_t)b * LK_ + kk * 16 + (lane & 15)) * D_
                         + dblk * 32 + (lane >> 4) * 8;
    fx4 f0 = *(const fx4*)src;
    fx4 f1 = *(const fx4*)(src + 4);
    bf16x8 w;
#pragma unroll
    for (int j = 0; j < 4; ++j) { w[j] = (__bf16)f0[j]; w[4 + j] = (__bf16)f1[j]; }
    *(bf16x8*)(kp + (size_t)f * 512 + lane * 8) = w;
}

// ---------- prep: V -> fragment-packed, slot-permuted bf16 ----------
// frag f = ((b*64 + ck)*8 + nb); elem e of lane(l15,g) = V[ck*32 + (e>>2)*16 + g*4 + (e&3)][nb*16+l15]
__global__ __launch_bounds__(256)
void vprep(const float* __restrict__ v, __bf16* __restrict__ vp)
{
    int id   = blockIdx.x * 256 + threadIdx.x;
    int lane = id & 63;
    int f    = id >> 6;
    int nb = f & 7, ck = (f >> 3) & 63, b = f >> 9;
    int l15 = lane & 15, g = lane >> 4;
    bf16x8 w;
#pragma unroll
    for (int e = 0; e < 8; ++e) {
        int key = ck * 32 + (e >> 2) * 16 + g * 4 + (e & 3);
        w[e] = (__bf16)v[((size_t)b * LK_ + key) * D_ + nb * 16 + l15];
    }
    *(bf16x8*)(vp + (size_t)f * 512 + lane * 8) = w;
}

// ---------- main: coalesced-fragment sigmoid attention ----------
// 8 waves: qg = wid&1 (32 q rows via 2 qq frags), kq = wid>>1 (32-key quarter of
// each 128-key iteration). All K/V loads are contiguous 1KB L2 bursts.
__global__ __launch_bounds__(THREADS, 2)
void sigattn_main(const float* __restrict__ q, const int* __restrict__ mask,
                  const __bf16* __restrict__ Kp, const __bf16* __restrict__ Vp,
                  float* __restrict__ out)
{
    __shared__ __align__(16) char smem[64 * 132 * 4];   // bits dbuf (5120B) / epilogue f32
    unsigned char* bitsbuf = (unsigned char*)smem;      // [2][64 rows][40 pad]

    const int tid  = threadIdx.x;
    const int lane = tid & 63;
    const int l15  = lane & 15;
    const int g    = lane >> 4;
    const int wid  = tid >> 6;
    const int qg   = wid & 1;
    const int kq   = wid >> 1;            // 0..3
    const int qbase = qg * 32;

    const int bid = blockIdx.x;
    const int b   = bid & 7;              // batch -> XCD-pinned packed K/V in L2
    const int q0  = (bid >> 3) * QBLK;

    const float*  qb = q    + ((size_t)b * LQ_ + q0) * D_;
    const int*    mb = mask + ((size_t)b * LQ_ + q0) * LK_;
    const __bf16* kp = Kp + (size_t)b * 262144;
    const __bf16* vp = Vp + (size_t)b * 262144;
    float*        ob = out  + ((size_t)b * LQ_ + q0) * D_;

    // Q fragments (registers for whole kernel)
    bf16x8 qfrag[2][4];
#pragma unroll
    for (int qq = 0; qq < 2; ++qq) {
        const float* qrow = qb + (size_t)(qbase + qq * 16 + l15) * D_;
#pragma unroll
        for (int dblk = 0; dblk < 4; ++dblk) {
            fx4 f0 = *(const fx4*)(qrow + dblk * 32 + g * 8);
            fx4 f1 = *(const fx4*)(qrow + dblk * 32 + g * 8 + 4);
            bf16x8 w;
#pragma unroll
            for (int j = 0; j < 4; ++j) { w[j] = (__bf16)f0[j]; w[4 + j] = (__bf16)f1[j]; }
            qfrag[qq][dblk] = w;
        }
    }

    // mask producer geometry: wave covers rows [wid*8, wid*8+8), 128 keys/iter
    const int prow = wid * 8 + (lane >> 5);          // + j*2
    const int pk4  = lane & 31;                      // nibble column (key/4 within iter)
    const int* mrow = mb + (size_t)prow * LK_ + pk4 * 4;

    // prologue: mask nibbles for iter 0
    {
        i32x4 m4[4];
#pragma unroll
        for (int j = 0; j < 4; ++j)
            m4[j] = __builtin_nontemporal_load((const i32x4*)(mrow + (size_t)(j * 2) * LK_));
#pragma unroll
        for (int j = 0; j < 4; ++j) {
            unsigned int nib = (m4[j][0] != 0 ? 1u : 0u) | (m4[j][1] != 0 ? 2u : 0u)
                             | (m4[j][2] != 0 ? 4u : 0u) | (m4[j][3] != 0 ? 8u : 0u);
            bitsbuf[(prow + j * 2) * 40 + pk4] = (unsigned char)nib;
        }
    }
    // K fragments for iter 0
    bf16x8 Kc[2][4];
#pragma unroll
    for (int ksl = 0; ksl < 2; ++ksl)
#pragma unroll
        for (int dblk = 0; dblk < 4; ++dblk)
            Kc[ksl][dblk] = *(const bf16x8*)(kp + (size_t)(((kq * 2 + ksl) * 4 + dblk)) * 512 + lane * 8);

    asm volatile("s_waitcnt lgkmcnt(0)\n\ts_barrier" ::: "memory");

    f32x4 oacc[2][8];
#pragma unroll
    for (int qq = 0; qq < 2; ++qq)
#pragma unroll
        for (int nb = 0; nb < 8; ++nb) oacc[qq][nb] = (f32x4){0.f, 0.f, 0.f, 0.f};

    for (int i = 0; i < NITER; ++i) {
        const bool more = (i + 1 < NITER);

        // ---- V fragments for this iter (consumed after sigmoid; latency hides) ----
        bf16x8 vfr[8];
#pragma unroll
        for (int nb = 0; nb < 8; ++nb)
            vfr[nb] = *(const bf16x8*)(vp + (size_t)(((i * 4 + kq) * 8 + nb)) * 512 + lane * 8);

        // ---- mask prefetch for iter i+1 (coalesced int4, nontemporal) ----
        i32x4 m4[4];
        if (more) {
#pragma unroll
            for (int j = 0; j < 4; ++j)
                m4[j] = __builtin_nontemporal_load(
                    (const i32x4*)(mrow + (size_t)(i + 1) * 128 + (size_t)(j * 2) * LK_));
        }

        // ---- QK^T swapped: sacc[qq][ksl] (rows=keys, cols=q) ----
        f32x4 sacc[2][2];
#pragma unroll
        for (int qq = 0; qq < 2; ++qq)
#pragma unroll
            for (int ksl = 0; ksl < 2; ++ksl) sacc[qq][ksl] = (f32x4){0.f, 0.f, 0.f, 0.f};
#pragma unroll
        for (int ksl = 0; ksl < 2; ++ksl)
#pragma unroll
            for (int dblk = 0; dblk < 4; ++dblk) {
                bf16x8 a = Kc[ksl][dblk];
#pragma unroll
                for (int qq = 0; qq < 2; ++qq)
                    sacc[qq][ksl] = __builtin_amdgcn_mfma_f32_16x16x32_bf16(a, qfrag[qq][dblk], sacc[qq][ksl], 0, 0, 0);
            }

        // ---- K prefetch for iter i+1 (stays in flight across the asm barrier) ----
        bf16x8 Kn[2][4];
        if (more) {
#pragma unroll
            for (int ksl = 0; ksl < 2; ++ksl)
#pragma unroll
                for (int dblk = 0; dblk < 4; ++dblk)
                    Kn[ksl][dblk] = *(const bf16x8*)(kp + (size_t)((((i + 1) * 8 + kq * 2 + ksl) * 4 + dblk)) * 512 + lane * 8);
        }

        // ---- mask bits + sigmoid -> P fragments (registers only) ----
        bf16x8 pfrag[2];
#pragma unroll
        for (int qq = 0; qq < 2; ++qq) {
            const int rrow = (qbase + qq * 16 + l15) * 40;
            unsigned int b0 = bitsbuf[(i & 1) * 2560 + rrow + kq * 8 + g];
            unsigned int b1 = bitsbuf[(i & 1) * 2560 + rrow + kq * 8 + 4 + g];
#pragma unroll
            for (int ksl = 0; ksl < 2; ++ksl) {
                unsigned int bb = ksl ? b1 : b0;
#pragma unroll
                for (int r = 0; r < 4; ++r) {
                    float e = exp2f(sacc[qq][ksl][r] * NEGL2E);
                    float p = __builtin_amdgcn_rcpf(1.0f + e);
                    p = ((bb >> r) & 1u) ? 0.0f : p;
                    pfrag[qq][ksl * 4 + r] = (__bf16)p;
                }
            }
        }

        // ---- PV ----
#pragma unroll
        for (int nb = 0; nb < 8; ++nb)
#pragma unroll
            for (int qq = 0; qq < 2; ++qq)
                oacc[qq][nb] = __builtin_amdgcn_mfma_f32_16x16x32_bf16(pfrag[qq], vfr[nb], oacc[qq][nb], 0, 0, 0);

        // ---- write next iter's nibbles ----
        if (more) {
#pragma unroll
            for (int j = 0; j < 4; ++j) {
                unsigned int nib = (m4[j][0] != 0 ? 1u : 0u) | (m4[j][1] != 0 ? 2u : 0u)
                                 | (m4[j][2] != 0 ? 4u : 0u) | (m4[j][3] != 0 ? 8u : 0u);
                bitsbuf[((i + 1) & 1) * 2560 + (prow + j * 2) * 40 + pk4] = (unsigned char)nib;
            }
        }

        // barrier: drain LDS only; K prefetch (vmcnt) stays outstanding
        asm volatile("s_waitcnt lgkmcnt(0)\n\ts_barrier" ::: "memory");

        if (more) {
#pragma unroll
            for (int ksl = 0; ksl < 2; ++ksl)
#pragma unroll
                for (int dblk = 0; dblk < 4; ++dblk)
                    Kc[ksl][dblk] = Kn[ksl][dblk];
        }
    }

    // ---------------- epilogue: reduce the 4 kq partials, store ----------------
    __syncthreads();
    float* red = (float*)smem;     // [64][132]
    if (kq == 0) {
#pragma unroll
        for (int qq = 0; qq < 2; ++qq)
#pragma unroll
            for (int nb = 0; nb < 8; ++nb)
#pragma unroll
                for (int r = 0; r < 4; ++r)
                    red[(qbase + qq * 16 + 4 * g + r) * 132 + nb * 16 + l15] = oacc[qq][nb][r];
    }
    __syncthreads();
    if (kq == 1) {
#pragma unroll
        for (int qq = 0; qq < 2; ++qq)
#pragma unroll
            for (int nb = 0; nb < 8; ++nb)
#pragma unroll
                for (int r = 0; r < 4; ++r)
                    red[(qbase + qq * 16 + 4 * g + r) * 132 + nb * 16 + l15] += oacc[qq][nb][r];
    }
    __syncthreads();
    if (kq == 2) {
#pragma unroll
        for (int qq = 0; qq < 2; ++qq)
#pragma unroll
            for (int nb = 0; nb < 8; ++nb)
#pragma unroll
                for (int r = 0; r < 4; ++r)
                    red[(qbase + qq * 16 + 4 * g + r) * 132 + nb * 16 + l15] += oacc[qq][nb][r];
    }
    __syncthreads();
    if (kq == 3) {
#pragma unroll
        for (int qq = 0; qq < 2; ++qq)
#pragma unroll
            for (int nb = 0; nb < 8; ++nb)
#pragma unroll
                for (int r = 0; r < 4; ++r)
                    red[(qbase + qq * 16 + 4 * g + r) * 132 + nb * 16 + l15] += oacc[qq][nb][r];
    }
    __syncthreads();
#pragma unroll
    for (int i2 = 0; i2 < 4; ++i2) {
        int idx = tid + i2 * THREADS;
        int row = idx >> 5, c4 = idx & 31;
        fx4 val = *(const fx4*)(red + row * 132 + c4 * 4);
        __builtin_nontemporal_store(val, (fx4*)(ob + (size_t)row * D_ + c4 * 4));
    }
}

extern "C" void kernel_launch(void* const* d_in, const int* in_sizes, int n_in,
                              void* d_out, int out_size, void* d_ws, size_t ws_size,
                              hipStream_t stream) {
    const float* q    = (const float*)d_in[0];
    const float* k    = (const float*)d_in[1];
    const float* v    = (const float*)d_in[2];
    const int*   mask = (const int*)d_in[3];
    float*       out  = (float*)d_out;

    __bf16* Kp = (__bf16*)d_ws;                       // 4 MB packed K frags
    __bf16* Vp = (__bf16*)d_ws + (size_t)2097152;     // 4 MB packed V frags

    kprep<<<dim3(1024), dim3(256), 0, stream>>>(k, Kp);
    vprep<<<dim3(1024), dim3(256), 0, stream>>>(v, Vp);
    sigattn_main<<<dim3(256), dim3(THREADS), 0, stream>>>(q, mask, Kp, Vp, out);
}